// Round 2
// baseline (323.715 us; speedup 1.0000x reference)
//
#include <hip/hip_runtime.h>
#include <hip/hip_bf16.h>

// Problem constants (fixed by reference)
#define NPTS  8192
#define GXD   334
#define GYD   334
#define GZD   2
#define HSIZE 16384
#define HMASK 16383
#define KADJ  50
#define TROUNDS 24

__device__ __forceinline__ unsigned hashv(unsigned v) {
    unsigned h = v * 2654435761u;
    h ^= h >> 15;
    return h & HMASK;
}

__device__ __forceinline__ void voxel_coords(float x, float y, float z,
                                             int& cx, int& cy, int& cz) {
    // Mirror ref exactly: floor((p - PC_MIN) / VOXEL), clip after cast.
    cx = (int)floorf((x - (-50.0f)) / 0.3f);
    cy = (int)floorf((y - (-50.0f)) / 0.3f);
    cz = (int)floorf((z - (-5.0f))  / 6.0f);
    cx = min(max(cx, 0), GXD - 1);
    cy = min(max(cy, 0), GYD - 1);
    cz = min(max(cz, 0), GZD - 1);
}

__global__ void k_init(int* hkey, float* hcnt, float* hsx, float* hsy, float* hsz, int* hrep) {
    int i = blockIdx.x * blockDim.x + threadIdx.x;
    if (i < HSIZE) {
        hkey[i] = -1;
        hcnt[i] = 0.0f;
        hsx[i] = 0.0f; hsy[i] = 0.0f; hsz[i] = 0.0f;
        hrep[i] = 0x7FFFFFFF;
    }
}

__global__ void k_accum(const float* __restrict__ pts, const int* __restrict__ bidx,
                        int* hkey, float* hcnt, float* hsx, float* hsy, float* hsz,
                        int* hrep, int* pslot) {
    int i = blockIdx.x * blockDim.x + threadIdx.x;
    if (i >= NPTS) return;
    float x = pts[3 * i + 0], y = pts[3 * i + 1], z = pts[3 * i + 2];
    int cx, cy, cz;
    voxel_coords(x, y, z, cx, cy, cz);
    int b = bidx[i];
    int vid = ((b * GZD + cz) * GYD + cy) * GXD + cx;
    unsigned h = hashv((unsigned)vid);
    int slot;
    for (;;) {
        int prev = atomicCAS(&hkey[h], -1, vid);
        if (prev == -1 || prev == vid) { slot = (int)h; break; }
        h = (h + 1) & HMASK;
    }
    atomicAdd(&hcnt[slot], 1.0f);
    atomicAdd(&hsx[slot], x);
    atomicAdd(&hsy[slot], y);
    atomicAdd(&hsz[slot], z);
    atomicMin(&hrep[slot], i);
    pslot[i] = slot;
}

__global__ void k_centers(const int* __restrict__ hkey, const float* __restrict__ hcnt,
                          const float* __restrict__ hsx, const float* __restrict__ hsy,
                          const float* __restrict__ hsz,
                          float* vcx, float* vcy, float* vcz) {
    int i = blockIdx.x * blockDim.x + threadIdx.x;
    if (i < HSIZE && hkey[i] != -1) {
        float cn = fmaxf(hcnt[i], 1.0f);   // ref: sums / maximum(cnt, 1)
        vcx[i] = hsx[i] / cn;
        vcy[i] = hsy[i] / cn;
        vcz[i] = hsz[i] / cn;
    }
}

__device__ __forceinline__ int hlookup(const int* __restrict__ hkey, int vid) {
    unsigned h = hashv((unsigned)vid);
    for (;;) {
        int k = hkey[h];
        if (k == vid) return (int)h;
        if (k == -1)  return -1;
        h = (h + 1) & HMASK;
    }
}

__global__ void k_gather_adj(const float* __restrict__ pts, const int* __restrict__ bidx,
                             const int* __restrict__ hkey, const int* __restrict__ pslot,
                             const float* __restrict__ vcx, const float* __restrict__ vcy,
                             const float* __restrict__ vcz, const int* __restrict__ hrep,
                             int* __restrict__ deg, int* __restrict__ adj,
                             float* __restrict__ out) {
    int i = blockIdx.x * blockDim.x + threadIdx.x;
    if (i >= NPTS) return;
    float x = pts[3 * i + 0], y = pts[3 * i + 1], z = pts[3 * i + 2];
    int cx, cy, cz;
    voxel_coords(x, y, z, cx, cy, cz);
    int b = bidx[i];
    int slot = pslot[i];
    float cxf = vcx[slot], cyf = vcy[slot], czf = vcz[slot];

    // Outputs (float32): cluster_inds interleaved [b,c], valid, cpp centers.
    out[2 * i]                = (float)b;
    out[2 * NPTS + i]         = 1.0f;          // valid: cnt >= MIN_POINTS=1 always
    out[3 * NPTS + 3 * i + 0] = cxf;
    out[3 * NPTS + 3 * i + 1] = cyf;
    out[3 * NPTS + 3 * i + 2] = czf;

    // Adjacency: 5x5 xy window, both z layers, same batch. center-dist(xy) < 0.6
    // (xy index diff >= 3 provably exceeds 0.6, so the window is exact).
    int ne = 0;
    for (int zz = 0; zz < GZD; zz++) {
        for (int dy = -2; dy <= 2; dy++) {
            int ny = cy + dy;
            if (ny < 0 || ny >= GYD) continue;
            for (int dx = -2; dx <= 2; dx++) {
                int nx = cx + dx;
                if (nx < 0 || nx >= GXD) continue;
                int nvid = ((b * GZD + zz) * GYD + ny) * GXD + nx;
                int s = hlookup(hkey, nvid);
                if (s < 0) continue;
                float ddx = cxf - vcx[s];
                float ddy = cyf - vcy[s];
                // Block FMA contraction: ref computes dx*dx + dy*dy with separate roundings.
                float sq = __fadd_rn(__fmul_rn(ddx, ddx), __fmul_rn(ddy, ddy));
                float dist = sqrtf(sq);
                if (dist < 0.6f) {
                    adj[i * KADJ + ne] = hrep[s];   // representative = min point idx of that voxel
                    ne++;
                }
            }
        }
    }
    deg[i] = ne;
}

// Single-block CC: labels in LDS, min-label propagation + hooking + pointer jumping.
// Monotone (labels only decrease, always an index of a same-component vertex), so
// unsynchronized stale reads are safe; converges to component-min well within TROUNDS.
__global__ void __launch_bounds__(1024) k_cc(const int* __restrict__ adj,
                                             const int* __restrict__ deg,
                                             float* __restrict__ out) {
    __shared__ int l[NPTS];
    int t = threadIdx.x;
    for (int i = t; i < NPTS; i += 1024) l[i] = i;
    __syncthreads();
    for (int r = 0; r < TROUNDS; r++) {
        for (int i = t; i < NPTS; i += 1024) {
            int old = l[i];
            int m = old;
            int d = deg[i];
            const int* a = &adj[i * KADJ];
            for (int e = 0; e < d; e++) {
            int lj = l[a[e]];
                if (lj < m) m = lj;
            }
            if (m < old) {
                atomicMin(&l[i], m);
                atomicMin(&l[old], m);   // hook: merge trees at the old root
            }
        }
        __syncthreads();
        for (int jp = 0; jp < 2; jp++) {   // pointer jumping (compression)
            for (int i = t; i < NPTS; i += 1024) {
                int a2 = l[i];
                int b2 = l[a2];
                if (b2 < a2) l[i] = b2;
            }
            __syncthreads();
        }
    }
    // valid is always true -> cluster = label
    for (int i = t; i < NPTS; i += 1024)
        out[2 * i + 1] = (float)l[i];
}

extern "C" void kernel_launch(void* const* d_in, const int* in_sizes, int n_in,
                              void* d_out, int out_size, void* d_ws, size_t ws_size,
                              hipStream_t stream) {
    const float* pts  = (const float*)d_in[0];
    const int*   bidx = (const int*)d_in[1];
    float* out = (float*)d_out;

    char* w = (char*)d_ws;
    int*   hkey  = (int*)  (w + 0);        // 16384 ints
    float* hcnt  = (float*)(w + 65536);
    float* hsx   = (float*)(w + 131072);
    float* hsy   = (float*)(w + 196608);
    float* hsz   = (float*)(w + 262144);
    int*   hrep  = (int*)  (w + 327680);
    float* vcx   = (float*)(w + 393216);
    float* vcy   = (float*)(w + 458752);
    float* vcz   = (float*)(w + 524288);
    int*   pslot = (int*)  (w + 589824);   // 8192 ints
    int*   deg   = (int*)  (w + 622592);   // 8192 ints
    int*   adj   = (int*)  (w + 655360);   // 8192*50 ints  (~1.6 MB; total ws use ~2.2 MB)

    hipLaunchKernelGGL(k_init,       dim3(HSIZE / 256), dim3(256), 0, stream,
                       hkey, hcnt, hsx, hsy, hsz, hrep);
    hipLaunchKernelGGL(k_accum,      dim3(NPTS / 256),  dim3(256), 0, stream,
                       pts, bidx, hkey, hcnt, hsx, hsy, hsz, hrep, pslot);
    hipLaunchKernelGGL(k_centers,    dim3(HSIZE / 256), dim3(256), 0, stream,
                       hkey, hcnt, hsx, hsy, hsz, vcx, vcy, vcz);
    hipLaunchKernelGGL(k_gather_adj, dim3(NPTS / 256),  dim3(256), 0, stream,
                       pts, bidx, hkey, pslot, vcx, vcy, vcz, hrep, deg, adj, out);
    hipLaunchKernelGGL(k_cc,         dim3(1),           dim3(1024), 0, stream,
                       adj, deg, out);
}

// Round 3
// 66.528 us; speedup vs baseline: 4.8658x; 4.8658x over previous
//
#include <hip/hip_runtime.h>
#include <hip/hip_bf16.h>

// Problem constants (fixed by reference)
#define NPTS  8192
#define GXD   334
#define GYD   334
#define GZD   2
#define HSIZE 16384
#define HMASK 16383
#define KADJ  50
#define TROUNDS 24

__device__ __forceinline__ unsigned hashv(unsigned v) {
    unsigned h = v * 2654435761u;
    h ^= h >> 15;
    return h & HMASK;
}

__device__ __forceinline__ void voxel_coords(float x, float y, float z,
                                             int& cx, int& cy, int& cz) {
    // Mirror ref exactly: floor((p - PC_MIN) / VOXEL), clip after cast.
    cx = (int)floorf((x - (-50.0f)) / 0.3f);
    cy = (int)floorf((y - (-50.0f)) / 0.3f);
    cz = (int)floorf((z - (-5.0f))  / 6.0f);
    cx = min(max(cx, 0), GXD - 1);
    cy = min(max(cy, 0), GYD - 1);
    cz = min(max(cz, 0), GZD - 1);
}

__global__ void k_accum(const float* __restrict__ pts, const int* __restrict__ bidx,
                        int* hkey, float* hcnt, float* hsx, float* hsy, float* hsz,
                        int* hrep, int* pslot) {
    int i = blockIdx.x * blockDim.x + threadIdx.x;
    if (i >= NPTS) return;
    float x = pts[3 * i + 0], y = pts[3 * i + 1], z = pts[3 * i + 2];
    int cx, cy, cz;
    voxel_coords(x, y, z, cx, cy, cz);
    int b = bidx[i];
    int vid = ((b * GZD + cz) * GYD + cy) * GXD + cx;
    unsigned h = hashv((unsigned)vid);
    int slot;
    for (;;) {
        int prev = atomicCAS(&hkey[h], -1, vid);
        if (prev == -1 || prev == vid) { slot = (int)h; break; }
        h = (h + 1) & HMASK;
    }
    atomicAdd(&hcnt[slot], 1.0f);
    atomicAdd(&hsx[slot], x);
    atomicAdd(&hsy[slot], y);
    atomicAdd(&hsz[slot], z);
    atomicMin(&hrep[slot], i);
    pslot[i] = slot;
}

__device__ __forceinline__ int hlookup(const int* __restrict__ hkey, int vid) {
    unsigned h = hashv((unsigned)vid);
    for (;;) {
        int k = hkey[h];
        if (k == vid) return (int)h;
        if (k == -1)  return -1;
        h = (h + 1) & HMASK;
    }
}

// One 64-lane wave per point; lane c < 50 owns window cell (zz, dy, dx).
// 4 waves (256 threads) per block -> 2048 blocks.
__global__ void k_gather_adj(const float* __restrict__ pts, const int* __restrict__ bidx,
                             const int* __restrict__ hkey, const int* __restrict__ pslot,
                             const float* __restrict__ hcnt,
                             const float* __restrict__ hsx, const float* __restrict__ hsy,
                             const float* __restrict__ hsz, const int* __restrict__ hrep,
                             int* __restrict__ deg, int* __restrict__ adj,
                             float* __restrict__ out) {
    int wid  = threadIdx.x >> 6;            // wave within block
    int lane = threadIdx.x & 63;
    int i = blockIdx.x * 4 + wid;           // point index
    if (i >= NPTS) return;

    // Broadcast loads (same address across lanes)
    float x = pts[3 * i + 0], y = pts[3 * i + 1], z = pts[3 * i + 2];
    int cx, cy, cz;
    voxel_coords(x, y, z, cx, cy, cz);
    int b    = bidx[i];
    int slot = pslot[i];

    // Own voxel center (== ref: sums / max(cnt,1); identical f32 division)
    float cn  = fmaxf(hcnt[slot], 1.0f);
    float cxf = hsx[slot] / cn;
    float cyf = hsy[slot] / cn;
    float czf = hsz[slot] / cn;

    // Neighbor test: this lane's cell
    bool pred = false;
    int  rep  = 0;
    if (lane < KADJ) {
        int zz  = lane / 25;
        int rem = lane % 25;
        int dy  = rem / 5 - 2;
        int dx  = rem % 5 - 2;
        int ny = cy + dy, nx = cx + dx;
        if (ny >= 0 && ny < GYD && nx >= 0 && nx < GXD) {
            int nvid = ((b * GZD + zz) * GYD + ny) * GXD + nx;
            int s = hlookup(hkey, nvid);
            if (s >= 0) {
                float ncn = fmaxf(hcnt[s], 1.0f);
                float nxc = hsx[s] / ncn;
                float nyc = hsy[s] / ncn;
                float ddx = cxf - nxc;
                float ddy = cyf - nyc;
                // Separate roundings like ref (no FMA contraction)
                float sq = __fadd_rn(__fmul_rn(ddx, ddx), __fmul_rn(ddy, ddy));
                if (sqrtf(sq) < 0.6f) {
                    pred = true;
                    rep  = hrep[s];   // representative = min point idx of that voxel
                }
            }
        }
    }
    unsigned long long mask = __ballot(pred);
    if (pred) {
        int rank = __popcll(mask & ((1ull << lane) - 1ull));
        adj[i * KADJ + rank] = rep;
    }
    if (lane == 0) {
        deg[i] = __popcll(mask);
        // Outputs (float32): cluster_inds interleaved [b,c], valid, cpp centers.
        out[2 * i]                = (float)b;
        out[2 * NPTS + i]         = 1.0f;          // cnt >= MIN_POINTS=1 always
        out[3 * NPTS + 3 * i + 0] = cxf;
        out[3 * NPTS + 3 * i + 1] = cyf;
        out[3 * NPTS + 3 * i + 2] = czf;
    }
}

// Single-block CC: labels in LDS, min-label propagation + hooking + pointer jumping,
// with convergence early-exit. Labels are monotone-decreasing, always an index of a
// same-component vertex; a full round with no change implies all adjacent labels are
// equal => labels constant per component => constant == component min (monotone from
// identity). So breaking at no-change yields exactly the reference fixed point.
__global__ void __launch_bounds__(1024) k_cc(const int* __restrict__ adj,
                                             const int* __restrict__ deg,
                                             float* __restrict__ out) {
    __shared__ int l[NPTS];
    __shared__ int changed;
    int t = threadIdx.x;
    for (int i = t; i < NPTS; i += 1024) l[i] = i;
    __syncthreads();
    for (int r = 0; r < TROUNDS; r++) {
        __syncthreads();                 // separate prior round's flag read from reset
        if (t == 0) changed = 0;
        __syncthreads();
        // propagate + hook
        for (int i = t; i < NPTS; i += 1024) {
            int old = l[i];
            int m = old;
            int d = deg[i];
            const int* a = &adj[i * KADJ];
            for (int e = 0; e < d; e++) {
                int lj = l[a[e]];
                if (lj < m) m = lj;
            }
            if (m < old) {
                atomicMin(&l[i], m);
                atomicMin(&l[old], m);   // hook: merge trees at the old root
                changed = 1;
            }
        }
        __syncthreads();
        // pointer jumping (compression) x2
        for (int jp = 0; jp < 2; jp++) {
            for (int i = t; i < NPTS; i += 1024) {
                int a2 = l[i];
                int b2 = l[a2];
                if (b2 < a2) { l[i] = b2; changed = 1; }
            }
            __syncthreads();
        }
        if (!changed) break;             // uniform: read after barrier
    }
    // valid is always true -> cluster = label
    for (int i = t; i < NPTS; i += 1024)
        out[2 * i + 1] = (float)l[i];
}

extern "C" void kernel_launch(void* const* d_in, const int* in_sizes, int n_in,
                              void* d_out, int out_size, void* d_ws, size_t ws_size,
                              hipStream_t stream) {
    const float* pts  = (const float*)d_in[0];
    const int*   bidx = (const int*)d_in[1];
    float* out = (float*)d_out;

    char* w = (char*)d_ws;
    int*   hkey  = (int*)  (w + 0);        // 16384 ints
    float* hcnt  = (float*)(w + 65536);
    float* hsx   = (float*)(w + 131072);
    float* hsy   = (float*)(w + 196608);
    float* hsz   = (float*)(w + 262144);
    int*   hrep  = (int*)  (w + 327680);
    int*   pslot = (int*)  (w + 589824);   // 8192 ints
    int*   deg   = (int*)  (w + 622592);   // 8192 ints
    int*   adj   = (int*)  (w + 655360);   // 8192*50 ints (~1.6 MB; total ws ~2.2 MB)

    // Hash-table init via async memsets (replaces k_init kernel):
    hipMemsetAsync(hkey, 0xFF, HSIZE * sizeof(int), stream);            // keys = -1
    hipMemsetAsync(hcnt, 0x00, 4 * HSIZE * sizeof(float), stream);      // cnt,sx,sy,sz = 0
    hipMemsetAsync(hrep, 0x7F, HSIZE * sizeof(int), stream);            // reps = 0x7F7F7F7F (+inf)

    hipLaunchKernelGGL(k_accum,      dim3(NPTS / 256), dim3(256), 0, stream,
                       pts, bidx, hkey, hcnt, hsx, hsy, hsz, hrep, pslot);
    hipLaunchKernelGGL(k_gather_adj, dim3(NPTS / 4),   dim3(256), 0, stream,
                       pts, bidx, hkey, pslot, hcnt, hsx, hsy, hsz, hrep, deg, adj, out);
    hipLaunchKernelGGL(k_cc,         dim3(1),          dim3(1024), 0, stream,
                       adj, deg, out);
}